// Round 4
// baseline (549.355 us; speedup 1.0000x reference)
//
#include <hip/hip_runtime.h>
#include <hip/hip_bf16.h>
#include <math.h>

#define S_DIM 2048
#define B_DIM 64
#define H_DIM 1024
#define KP     8                    // k-split factor for the v GEMM
#define KCHUNK (H_DIM / KP)         // 128 k-rows per chunk
#define BLK_B  4                    // b's per block in v_partial
#define SBLK   (S_DIM / 64)         // 32 score blocks per b

typedef float f32x4 __attribute__((ext_vector_type(4)));

// ---------------------------------------------------------------------------
// Kernel 1: partial[p,b,h] = sum_{k in chunk p} hidden[b,k] * W[k,h]
// Grid (KP, B/BLK_B) = (8,16) = 128 blocks. Each block serves BLK_B=4 b's from
// one W-row read (W logical traffic 256MB -> 64MB vs round-2). hidden slice
// staged in LDS (broadcast reads, no conflicts).
// NOTE: bias term is dropped everywhere — hidden.bias is constant per row b
// and softmax is shift-invariant, so it cancels exactly.
// ---------------------------------------------------------------------------
__global__ __launch_bounds__(256) void v_partial_kernel(
    const float* __restrict__ hidden,   // [B,H]
    const float* __restrict__ W,        // [H,H]
    float* __restrict__ partial)        // [KP,B,H]
{
    const int p   = blockIdx.x;
    const int b0  = blockIdx.y * BLK_B;
    const int tid = threadIdx.x;
    const int h0  = tid * 4;
    const int k0  = p * KCHUNK;

    __shared__ float s_hid[BLK_B][KCHUNK];
#pragma unroll
    for (int r = 0; r < (BLK_B * KCHUNK) / 256; ++r) {
        const int i  = tid + r * 256;
        const int bb = i / KCHUNK;
        const int kk = i % KCHUNK;
        s_hid[bb][kk] = hidden[(size_t)(b0 + bb) * H_DIM + k0 + kk];
    }
    __syncthreads();

    f32x4 acc[BLK_B];
#pragma unroll
    for (int bb = 0; bb < BLK_B; ++bb) acc[bb] = (f32x4)0.f;

#pragma unroll 4
    for (int k = 0; k < KCHUNK; ++k) {
        const f32x4 w = *reinterpret_cast<const f32x4*>(W + (size_t)(k0 + k) * H_DIM + h0);
#pragma unroll
        for (int bb = 0; bb < BLK_B; ++bb) {
            const float hk = s_hid[bb][k];
            acc[bb].x = fmaf(hk, w.x, acc[bb].x);
            acc[bb].y = fmaf(hk, w.y, acc[bb].y);
            acc[bb].z = fmaf(hk, w.z, acc[bb].z);
            acc[bb].w = fmaf(hk, w.w, acc[bb].w);
        }
    }

#pragma unroll
    for (int bb = 0; bb < BLK_B; ++bb)
        *reinterpret_cast<f32x4*>(partial + ((size_t)p * B_DIM + b0 + bb) * H_DIM + h0) = acc[bb];
}

// ---------------------------------------------------------------------------
// Kernel 2: v[b,h] = sum_p partial[p,b,h]; also zeroes the softmax semaphores
// for kernel 3 (stream order guarantees this completes first -> fresh counters
// on every call, graph-replay safe).
// ---------------------------------------------------------------------------
__global__ __launch_bounds__(256) void v_reduce_kernel(
    const float* __restrict__ partial,  // [KP,B,H]
    float* __restrict__ v,              // [B,H]
    unsigned int* __restrict__ cnt)     // [B]
{
    const int b   = blockIdx.x;
    const int tid = threadIdx.x;
    const int h0  = tid * 4;

    f32x4 s = (f32x4)0.f;
#pragma unroll
    for (int p = 0; p < KP; ++p)
        s += *reinterpret_cast<const f32x4*>(partial + ((size_t)p * B_DIM + b) * H_DIM + h0);
    *reinterpret_cast<f32x4*>(v + (size_t)b * H_DIM + h0) = s;

    if (b == 0 && tid < B_DIM) cnt[tid] = 0u;
}

// ---------------------------------------------------------------------------
// Kernel 3: scores[b,s] = dot(v[b,:], enc[s,b,:]); the last block per row b
// (split-K semaphore) then computes softmax(scores[b,:]) -> out[b,0,:].
// Grid (SBLK, B) = (32,64), 256 threads = 4 waves, 16 s per wave in pairs.
// ---------------------------------------------------------------------------
__global__ __launch_bounds__(256) void scores_softmax_kernel(
    const float* __restrict__ enc,      // [S,B,H]
    const float* __restrict__ v,        // [B,H]
    float* __restrict__ scores,         // [B,S] (ws)
    float* __restrict__ out,            // [B,1,S]
    unsigned int* __restrict__ cnt)     // [B]
{
    const int b      = blockIdx.y;
    const int wave   = threadIdx.x >> 6;
    const int lane   = threadIdx.x & 63;
    const int s_base = blockIdx.x * 64 + wave * 16;

    const float* vb = v + (size_t)b * H_DIM;
    const int o = lane * 4;
    const f32x4 v0 = *reinterpret_cast<const f32x4*>(vb + o);
    const f32x4 v1 = *reinterpret_cast<const f32x4*>(vb + o + 256);
    const f32x4 v2 = *reinterpret_cast<const f32x4*>(vb + o + 512);
    const f32x4 v3 = *reinterpret_cast<const f32x4*>(vb + o + 768);

#pragma unroll 2
    for (int i = 0; i < 16; i += 2) {
        const float* ea = enc + ((size_t)(s_base + i) * B_DIM + b) * H_DIM;
        const float* eb = ea + (size_t)B_DIM * H_DIM;   // next s row

        const f32x4 a0 = __builtin_nontemporal_load(reinterpret_cast<const f32x4*>(ea + o));
        const f32x4 a1 = __builtin_nontemporal_load(reinterpret_cast<const f32x4*>(ea + o + 256));
        const f32x4 a2 = __builtin_nontemporal_load(reinterpret_cast<const f32x4*>(ea + o + 512));
        const f32x4 a3 = __builtin_nontemporal_load(reinterpret_cast<const f32x4*>(ea + o + 768));
        const f32x4 b0 = __builtin_nontemporal_load(reinterpret_cast<const f32x4*>(eb + o));
        const f32x4 b1 = __builtin_nontemporal_load(reinterpret_cast<const f32x4*>(eb + o + 256));
        const f32x4 b2 = __builtin_nontemporal_load(reinterpret_cast<const f32x4*>(eb + o + 512));
        const f32x4 b3 = __builtin_nontemporal_load(reinterpret_cast<const f32x4*>(eb + o + 768));

        float acc_a = v0.x * a0.x + v0.y * a0.y + v0.z * a0.z + v0.w * a0.w
                    + v1.x * a1.x + v1.y * a1.y + v1.z * a1.z + v1.w * a1.w
                    + v2.x * a2.x + v2.y * a2.y + v2.z * a2.z + v2.w * a2.w
                    + v3.x * a3.x + v3.y * a3.y + v3.z * a3.z + v3.w * a3.w;
        float acc_b = v0.x * b0.x + v0.y * b0.y + v0.z * b0.z + v0.w * b0.w
                    + v1.x * b1.x + v1.y * b1.y + v1.z * b1.z + v1.w * b1.w
                    + v2.x * b2.x + v2.y * b2.y + v2.z * b2.z + v2.w * b2.w
                    + v3.x * b3.x + v3.y * b3.y + v3.z * b3.z + v3.w * b3.w;

#pragma unroll
        for (int off = 32; off > 0; off >>= 1) {
            acc_a += __shfl_xor(acc_a, off);
            acc_b += __shfl_xor(acc_b, off);
        }

        if (lane == 0) {
            scores[(size_t)b * S_DIM + s_base + i]     = acc_a;
            scores[(size_t)b * S_DIM + s_base + i + 1] = acc_b;
        }
    }

    // ---- split-K semaphore: last block of row b does the softmax ----
    __shared__ bool s_last;
    __threadfence();                       // release scores to device scope
    if (threadIdx.x == 0) {
        const unsigned int prev = atomicAdd(&cnt[b], 1u);
        s_last = (prev == SBLK - 1);
    }
    __syncthreads();
    if (!s_last) return;
    __threadfence();                       // acquire other blocks' scores

    const int tid = threadIdx.x;
    const float* row = scores + (size_t)b * S_DIM;

    float vals[8];
    float m = -INFINITY;
#pragma unroll
    for (int i = 0; i < 8; ++i) {
        vals[i] = row[tid + i * 256];
        m = fmaxf(m, vals[i]);
    }

    __shared__ float red[256];
    red[tid] = m;
    __syncthreads();
    for (int off = 128; off > 0; off >>= 1) {
        if (tid < off) red[tid] = fmaxf(red[tid], red[tid + off]);
        __syncthreads();
    }
    m = red[0];
    __syncthreads();

    float sum = 0.f;
#pragma unroll
    for (int i = 0; i < 8; ++i) {
        vals[i] = __expf(vals[i] - m);
        sum += vals[i];
    }
    red[tid] = sum;
    __syncthreads();
    for (int off = 128; off > 0; off >>= 1) {
        if (tid < off) red[tid] += red[tid + off];
        __syncthreads();
    }
    const float inv = 1.0f / red[0];
    __syncthreads();

#pragma unroll
    for (int i = 0; i < 8; ++i)
        out[(size_t)b * S_DIM + tid + i * 256] = vals[i] * inv;
}

// ---------------------------------------------------------------------------
extern "C" void kernel_launch(void* const* d_in, const int* in_sizes, int n_in,
                              void* d_out, int out_size, void* d_ws, size_t ws_size,
                              hipStream_t stream) {
    const float* hidden = (const float*)d_in[0];   // [1,B,H]
    const float* enc    = (const float*)d_in[1];   // [S,B,H]
    const float* W      = (const float*)d_in[2];   // [H,H]
    // d_in[3] = bias: unused — constant per-row shift cancels in softmax.
    float* out          = (float*)d_out;           // [B,1,S]

    float* ws          = (float*)d_ws;
    float* partial     = ws;                                    // KP*B*H (2 MB)
    float* v           = partial + (size_t)KP * B_DIM * H_DIM;  // B*H (256 KB)
    float* scores      = v + (size_t)B_DIM * H_DIM;             // B*S (512 KB)
    unsigned int* cnt  = (unsigned int*)(scores + (size_t)B_DIM * S_DIM); // B

    v_partial_kernel<<<dim3(KP, B_DIM / BLK_B), dim3(256), 0, stream>>>(hidden, W, partial);
    v_reduce_kernel<<<dim3(B_DIM), dim3(256), 0, stream>>>(partial, v, cnt);
    scores_softmax_kernel<<<dim3(SBLK, B_DIM), dim3(256), 0, stream>>>(enc, v, scores, out, cnt);
}

// Round 5
// 102.648 us; speedup vs baseline: 5.3519x; 5.3519x over previous
//
#include <hip/hip_runtime.h>
#include <hip/hip_bf16.h>
#include <math.h>

#define S_DIM 2048
#define B_DIM 64
#define H_DIM 1024
#define KP     8                    // k-split factor for the v GEMM
#define KCHUNK (H_DIM / KP)         // 128 k-rows per chunk
#define BLK_B  4                    // b's per block in v_partial

typedef float f32x4 __attribute__((ext_vector_type(4)));

// ---------------------------------------------------------------------------
// Kernel 1: partial[p,b,h] = sum_{k in chunk p} hidden[b,k] * W[k,h]
// Grid (KP, B/BLK_B) = (8,16) = 128 blocks. Each block serves BLK_B=4 b's from
// one W-row read. hidden slice staged in LDS (broadcast reads).
// Bias is dropped everywhere: hidden.bias is a constant shift per row b and
// cancels in softmax.
// ---------------------------------------------------------------------------
__global__ __launch_bounds__(256) void v_partial_kernel(
    const float* __restrict__ hidden,   // [B,H]
    const float* __restrict__ W,        // [H,H]
    float* __restrict__ partial)        // [KP,B,H]
{
    const int p   = blockIdx.x;
    const int b0  = blockIdx.y * BLK_B;
    const int tid = threadIdx.x;
    const int h0  = tid * 4;
    const int k0  = p * KCHUNK;

    __shared__ float s_hid[BLK_B][KCHUNK];
#pragma unroll
    for (int r = 0; r < (BLK_B * KCHUNK) / 256; ++r) {
        const int i  = tid + r * 256;
        const int bb = i / KCHUNK;
        const int kk = i % KCHUNK;
        s_hid[bb][kk] = hidden[(size_t)(b0 + bb) * H_DIM + k0 + kk];
    }
    __syncthreads();

    f32x4 acc[BLK_B];
#pragma unroll
    for (int bb = 0; bb < BLK_B; ++bb) acc[bb] = (f32x4)0.f;

#pragma unroll 4
    for (int k = 0; k < KCHUNK; ++k) {
        const f32x4 w = *reinterpret_cast<const f32x4*>(W + (size_t)(k0 + k) * H_DIM + h0);
#pragma unroll
        for (int bb = 0; bb < BLK_B; ++bb) {
            const float hk = s_hid[bb][k];
            acc[bb].x = fmaf(hk, w.x, acc[bb].x);
            acc[bb].y = fmaf(hk, w.y, acc[bb].y);
            acc[bb].z = fmaf(hk, w.z, acc[bb].z);
            acc[bb].w = fmaf(hk, w.w, acc[bb].w);
        }
    }

#pragma unroll
    for (int bb = 0; bb < BLK_B; ++bb)
        *reinterpret_cast<f32x4*>(partial + ((size_t)p * B_DIM + b0 + bb) * H_DIM + h0) = acc[bb];
}

// ---------------------------------------------------------------------------
// Kernel 2: v[b,h] = sum_p partial[p,b,h]
// ---------------------------------------------------------------------------
__global__ __launch_bounds__(256) void v_reduce_kernel(
    const float* __restrict__ partial,  // [KP,B,H]
    float* __restrict__ v)              // [B,H]
{
    const int b   = blockIdx.x;
    const int tid = threadIdx.x;
    const int h0  = tid * 4;

    f32x4 s = (f32x4)0.f;
#pragma unroll
    for (int p = 0; p < KP; ++p)
        s += *reinterpret_cast<const f32x4*>(partial + ((size_t)p * B_DIM + b) * H_DIM + h0);
    *reinterpret_cast<f32x4*>(v + (size_t)b * H_DIM + h0) = s;
}

// ---------------------------------------------------------------------------
// Kernel 3: scores[b,s] = dot(v[b,:], enc[s,b,:])
// Grid (S/64, B) = (32,64), 256 threads = 4 waves, 16 s per wave in pairs
// (8 x 16B loads in flight). enc streamed with nontemporal loads.
// NO fences, NO semaphores — device-scope coherence ops stall the TCCs
// (round-4 lesson: 2048 per-block __threadfence() = 7x slowdown).
// ---------------------------------------------------------------------------
__global__ __launch_bounds__(256) void scores_kernel(
    const float* __restrict__ enc,      // [S,B,H]
    const float* __restrict__ v,        // [B,H]
    float* __restrict__ scores)         // [B,S]
{
    const int b      = blockIdx.y;
    const int wave   = threadIdx.x >> 6;
    const int lane   = threadIdx.x & 63;
    const int s_base = blockIdx.x * 64 + wave * 16;

    const float* vb = v + (size_t)b * H_DIM;
    const int o = lane * 4;
    const f32x4 v0 = *reinterpret_cast<const f32x4*>(vb + o);
    const f32x4 v1 = *reinterpret_cast<const f32x4*>(vb + o + 256);
    const f32x4 v2 = *reinterpret_cast<const f32x4*>(vb + o + 512);
    const f32x4 v3 = *reinterpret_cast<const f32x4*>(vb + o + 768);

#pragma unroll 2
    for (int i = 0; i < 16; i += 2) {
        const float* ea = enc + ((size_t)(s_base + i) * B_DIM + b) * H_DIM;
        const float* eb = ea + (size_t)B_DIM * H_DIM;   // next s row

        const f32x4 a0 = __builtin_nontemporal_load(reinterpret_cast<const f32x4*>(ea + o));
        const f32x4 a1 = __builtin_nontemporal_load(reinterpret_cast<const f32x4*>(ea + o + 256));
        const f32x4 a2 = __builtin_nontemporal_load(reinterpret_cast<const f32x4*>(ea + o + 512));
        const f32x4 a3 = __builtin_nontemporal_load(reinterpret_cast<const f32x4*>(ea + o + 768));
        const f32x4 b0 = __builtin_nontemporal_load(reinterpret_cast<const f32x4*>(eb + o));
        const f32x4 b1 = __builtin_nontemporal_load(reinterpret_cast<const f32x4*>(eb + o + 256));
        const f32x4 b2 = __builtin_nontemporal_load(reinterpret_cast<const f32x4*>(eb + o + 512));
        const f32x4 b3 = __builtin_nontemporal_load(reinterpret_cast<const f32x4*>(eb + o + 768));

        float acc_a = v0.x * a0.x + v0.y * a0.y + v0.z * a0.z + v0.w * a0.w
                    + v1.x * a1.x + v1.y * a1.y + v1.z * a1.z + v1.w * a1.w
                    + v2.x * a2.x + v2.y * a2.y + v2.z * a2.z + v2.w * a2.w
                    + v3.x * a3.x + v3.y * a3.y + v3.z * a3.z + v3.w * a3.w;
        float acc_b = v0.x * b0.x + v0.y * b0.y + v0.z * b0.z + v0.w * b0.w
                    + v1.x * b1.x + v1.y * b1.y + v1.z * b1.z + v1.w * b1.w
                    + v2.x * b2.x + v2.y * b2.y + v2.z * b2.z + v2.w * b2.w
                    + v3.x * b3.x + v3.y * b3.y + v3.z * b3.z + v3.w * b3.w;

#pragma unroll
        for (int off = 32; off > 0; off >>= 1) {
            acc_a += __shfl_xor(acc_a, off);
            acc_b += __shfl_xor(acc_b, off);
        }

        if (lane == 0) {
            scores[(size_t)b * S_DIM + s_base + i]     = acc_a;
            scores[(size_t)b * S_DIM + s_base + i + 1] = acc_b;
        }
    }
}

// ---------------------------------------------------------------------------
// Kernel 4: out[b,0,s] = softmax over s of scores[b,:]
// One block per b; f32x4 vectorized row access (8 floats/thread).
// ---------------------------------------------------------------------------
__global__ __launch_bounds__(256) void softmax_kernel(
    const float* __restrict__ scores,   // [B,S]
    float* __restrict__ out)            // [B,1,S]
{
    const int b   = blockIdx.x;
    const int tid = threadIdx.x;
    const float* row = scores + (size_t)b * S_DIM;

    f32x4 va = *reinterpret_cast<const f32x4*>(row + tid * 8);
    f32x4 vb = *reinterpret_cast<const f32x4*>(row + tid * 8 + 4);

    float m = fmaxf(fmaxf(fmaxf(va.x, va.y), fmaxf(va.z, va.w)),
                    fmaxf(fmaxf(vb.x, vb.y), fmaxf(vb.z, vb.w)));

    __shared__ float red[256];
    red[tid] = m;
    __syncthreads();
    for (int off = 128; off > 0; off >>= 1) {
        if (tid < off) red[tid] = fmaxf(red[tid], red[tid + off]);
        __syncthreads();
    }
    m = red[0];
    __syncthreads();

    va.x = __expf(va.x - m); va.y = __expf(va.y - m);
    va.z = __expf(va.z - m); va.w = __expf(va.w - m);
    vb.x = __expf(vb.x - m); vb.y = __expf(vb.y - m);
    vb.z = __expf(vb.z - m); vb.w = __expf(vb.w - m);
    const float sum = va.x + va.y + va.z + va.w + vb.x + vb.y + vb.z + vb.w;

    red[tid] = sum;
    __syncthreads();
    for (int off = 128; off > 0; off >>= 1) {
        if (tid < off) red[tid] += red[tid + off];
        __syncthreads();
    }
    const float inv = 1.0f / red[0];
    __syncthreads();

    va *= inv;
    vb *= inv;
    *reinterpret_cast<f32x4*>(out + (size_t)b * S_DIM + tid * 8)     = va;
    *reinterpret_cast<f32x4*>(out + (size_t)b * S_DIM + tid * 8 + 4) = vb;
}

// ---------------------------------------------------------------------------
extern "C" void kernel_launch(void* const* d_in, const int* in_sizes, int n_in,
                              void* d_out, int out_size, void* d_ws, size_t ws_size,
                              hipStream_t stream) {
    const float* hidden = (const float*)d_in[0];   // [1,B,H]
    const float* enc    = (const float*)d_in[1];   // [S,B,H]
    const float* W      = (const float*)d_in[2];   // [H,H]
    // d_in[3] = bias: unused — constant per-row shift cancels in softmax.
    float* out          = (float*)d_out;           // [B,1,S]

    float* ws      = (float*)d_ws;
    float* partial = ws;                                    // KP*B*H (2 MB)
    float* v       = partial + (size_t)KP * B_DIM * H_DIM;  // B*H (256 KB)
    float* scores  = v + (size_t)B_DIM * H_DIM;             // B*S (512 KB)

    v_partial_kernel<<<dim3(KP, B_DIM / BLK_B), dim3(256), 0, stream>>>(hidden, W, partial);
    v_reduce_kernel<<<dim3(B_DIM), dim3(256), 0, stream>>>(partial, v);
    scores_kernel<<<dim3(S_DIM / 64, B_DIM), dim3(256), 0, stream>>>(enc, v, scores);
    softmax_kernel<<<dim3(B_DIM), dim3(256), 0, stream>>>(scores, out);
}